// Round 4
// baseline (469.952 us; speedup 1.0000x reference)
//
#include <hip/hip_runtime.h>
#include <hip/hip_bf16.h>
#include <math.h>

#define D_  1024
#define L_  1024
#define B_  4
#define H_  16
#define HD_ 64

typedef __attribute__((ext_vector_type(4))) short short4_t;
typedef __attribute__((ext_vector_type(8))) short short8_t;
typedef __attribute__((ext_vector_type(4))) float f4;
typedef unsigned short u16;

__device__ __forceinline__ f4 MF(short8_t a, short8_t b, f4 c) {
  return __builtin_amdgcn_mfma_f32_16x16x32_bf16(a, b, c, 0, 0, 0);
}
__device__ __forceinline__ unsigned fbits(float x) { return __builtin_bit_cast(unsigned, x); }
__device__ __forceinline__ float bf2f(unsigned short u) {
  return __builtin_bit_cast(float, (unsigned)u << 16);
}
__device__ __forceinline__ unsigned pack2hi(float x, float y) {
  return (fbits(x) >> 16) | (fbits(y) & 0xFFFF0000u);
}
__device__ __forceinline__ float bfres(float x) {  // x - trunc_bf16(x)
  return x - __builtin_bit_cast(float, fbits(x) & 0xFFFF0000u);
}
__device__ __forceinline__ void gload16(const void* g, void* l) {
  __builtin_amdgcn_global_load_lds(
      (const __attribute__((address_space(1))) unsigned*)g,
      (__attribute__((address_space(3))) unsigned*)l, 16, 0, 0);
}
// two b64 reads forming one MFMA frag; 128B rows, XOR-swizzled (involution)
__device__ __forceinline__ short8_t ldsfrag(const char* base, int row, int cb) {
  const char* p = base + row * 128;
  const int sw = (row & 7) << 4;
  union { short4_t q[2]; short8_t v; } u;
  u.q[0] = *(const short4_t*)(p + (cb ^ sw));
  u.q[1] = *(const short4_t*)(p + ((cb + 32) ^ sw));
  return u.v;
}

// ---------------------------------------------------------------------------
// Kernel 1: student weight generation -> bf16 hi/lo planes, K-permuted
// (within each 32-col block, k-quad q -> pos (q&3)*8+((q>>2)&1)*4 so one b128
//  at [row][8g] is a complete MFMA fragment).
// ---------------------------------------------------------------------------
__global__ __launch_bounds__(256) void wgen_kernel(
    const float* __restrict__ tw, const float* __restrict__ wl,
    const float* __restrict__ sc, const float* __restrict__ sh,
    u16* __restrict__ whi, u16* __restrict__ wlo) {
  size_t i4 = (size_t)blockIdx.x * 256 + threadIdx.x;
  size_t e = i4 * 4;
  int p = (int)(e >> 20);
  size_t rem = e & 0xFFFFFu;
  float a0 = wl[p * 2 + 0], a1 = wl[p * 2 + 1];
  float4 t0 = *(const float4*)&tw[((size_t)(p * 2 + 0) << 20) + rem];
  float4 t1 = *(const float4*)&tw[((size_t)(p * 2 + 1) << 20) + rem];
  float4 s4 = *(const float4*)&sc[e];
  float4 h4 = *(const float4*)&sh[e];
  float4 o;
  o.x = tanhf(a0 * t0.x + a1 * t1.x) * s4.x + h4.x;
  o.y = tanhf(a0 * t0.y + a1 * t1.y) * s4.y + h4.y;
  o.z = tanhf(a0 * t0.z + a1 * t1.z) * s4.z + h4.z;
  o.w = tanhf(a0 * t0.w + a1 * t1.w) * s4.w + h4.w;
  const int q = (int)((e & 1023) >> 2);
  const size_t off = (e & ~(size_t)1023) +
                     (q >> 3) * 32 + (q & 3) * 8 + ((q >> 2) & 1) * 4;
  uint2 hi; hi.x = pack2hi(o.x, o.y); hi.y = pack2hi(o.z, o.w);
  *(uint2*)&whi[off] = hi;
  uint2 lo; lo.x = pack2hi(bfres(o.x), bfres(o.y)); lo.y = pack2hi(bfres(o.z), bfres(o.w));
  *(uint2*)&wlo[off] = lo;
}

// ---------------------------------------------------------------------------
// Kernel 2: bias generation (f32)
// ---------------------------------------------------------------------------
__global__ __launch_bounds__(256) void bgen_kernel(
    const float* __restrict__ tb, const float* __restrict__ wl,
    const float* __restrict__ sc, const float* __restrict__ sh,
    float* __restrict__ b_out) {
  int i = blockIdx.x * 256 + threadIdx.x;
  int p = i >> 10;
  int o = i & 1023;
  float v = tanhf(wl[p * 2 + 0] * tb[(p * 2 + 0) * D_ + o] +
                  wl[p * 2 + 1] * tb[(p * 2 + 1) * D_ + o]);
  b_out[i] = v * sc[i] + sh[i];
}

// ---------------------------------------------------------------------------
// Kernel 2b: dist_emb f32 -> bf16 (row-major, natural order)
// ---------------------------------------------------------------------------
__global__ __launch_bounds__(256) void ecvt_kernel(
    const float* __restrict__ emb, u16* __restrict__ embh) {
  int i4 = blockIdx.x * 256 + threadIdx.x;
  if (i4 >= 32752) return;   // 2047*64/4
  int e = i4 * 4;
  float4 v = *(const float4*)&emb[e];
  uint2 h2; h2.x = pack2hi(v.x, v.y); h2.y = pack2hi(v.z, v.w);
  *(uint2*)&embh[e] = h2;
}

// ---------------------------------------------------------------------------
// Kernel 3: QKV projection, bf16x3 MFMA; writes six bf16 planes:
// Qhi/Qlo, Khi/Klo as [b,h,l,hd]; Vthi/Vtlo TRANSPOSED as [b,h,hd,l].
// ---------------------------------------------------------------------------
__global__ __launch_bounds__(256) void proj_mfma_kernel(
    const float* __restrict__ hs,
    const u16* __restrict__ Bhp, const u16* __restrict__ Blp,
    const float* __restrict__ bias,
    u16* __restrict__ Qhi, u16* __restrict__ Qlo,
    u16* __restrict__ Khi, u16* __restrict__ Klo,
    u16* __restrict__ Vthi, u16* __restrict__ Vtlo) {
  __shared__ u16 Ah[128][32], Al[128][32], Bh[128][32], Bl[128][32];
  const int tid  = threadIdx.x;
  const int lane = tid & 63;
  const int wv   = tid >> 6;
  const int wm   = wv >> 1, wn = wv & 1;
  const int l15  = lane & 15, g = lane >> 4;

  const int bid = (blockIdx.x & 7) * 96 + (blockIdx.x >> 3);  // XCD swizzle
  const int mt = bid & 31, nt = bid >> 5;
  const int m0 = mt * 128, n0 = nt * 128;

  f4 acc[4][4];
#pragma unroll
  for (int i = 0; i < 4; ++i)
#pragma unroll
    for (int j = 0; j < 4; ++j) acc[i][j] = f4{0.f, 0.f, 0.f, 0.f};

#pragma unroll 1
  for (int k0 = 0; k0 < D_; k0 += 32) {
    // B: gload16 from pre-permuted planes (4 instr / wave)
#pragma unroll
    for (int s = 0; s < 4; ++s) {
      int q = wv * 4 + s;
      int plane = q >> 3, rowg = q & 7;
      const u16* src = (plane ? Blp : Bhp) +
                       (size_t)(n0 + rowg * 16 + (lane >> 2)) * 1024 + k0 + (lane & 3) * 8;
      u16* dst = (plane ? &Bl[0][0] : &Bh[0][0]) + rowg * 512;
      gload16(src, dst);
    }
    // A: reg-stage f32 hs, split hi/lo, write permuted
#pragma unroll
    for (int c = 0; c < 4; ++c) {
      int f4id = tid + c * 256;
      int row = f4id >> 3, q4 = f4id & 7;
      float4 v = *(const float4*)&hs[(size_t)(m0 + row) * 1024 + k0 + q4 * 4];
      int col = (q4 & 3) * 8 + ((q4 >> 2) & 1) * 4;
      uint2 hi2; hi2.x = pack2hi(v.x, v.y); hi2.y = pack2hi(v.z, v.w);
      *(uint2*)&Ah[row][col] = hi2;
      uint2 lo2; lo2.x = pack2hi(bfres(v.x), bfres(v.y)); lo2.y = pack2hi(bfres(v.z), bfres(v.w));
      *(uint2*)&Al[row][col] = lo2;
    }
    __syncthreads();

    short8_t ah[4], al[4], bh[4], bl[4];
#pragma unroll
    for (int i = 0; i < 4; ++i) {
      ah[i] = *(const short8_t*)&Ah[wm * 64 + i * 16 + l15][g * 8];
      al[i] = *(const short8_t*)&Al[wm * 64 + i * 16 + l15][g * 8];
      bh[i] = *(const short8_t*)&Bh[wn * 64 + i * 16 + l15][g * 8];
      bl[i] = *(const short8_t*)&Bl[wn * 64 + i * 16 + l15][g * 8];
    }
#pragma unroll
    for (int mi = 0; mi < 4; ++mi)
#pragma unroll
      for (int ni = 0; ni < 4; ++ni) {
        acc[mi][ni] = MF(ah[mi], bh[ni], acc[mi][ni]);
        acc[mi][ni] = MF(ah[mi], bl[ni], acc[mi][ni]);
        acc[mi][ni] = MF(al[mi], bh[ni], acc[mi][ni]);
      }
    __syncthreads();
  }

  const int p = n0 >> 10;
  const int nbase = n0 + wn * 64;
  float bnv[4];
#pragma unroll
  for (int ni = 0; ni < 4; ++ni) bnv[ni] = bias[nbase + ni * 16 + l15];
#pragma unroll
  for (int mi = 0; mi < 4; ++mi) {
#pragma unroll
    for (int r = 0; r < 4; ++r) {
      const int m = m0 + wm * 64 + mi * 16 + 4 * g + r;
      const int bb = m >> 10, l = m & 1023;
#pragma unroll
      for (int ni = 0; ni < 4; ++ni) {
        const int n = nbase + ni * 16 + l15;
        const int hd = n & 63, hh = (n >> 6) & 15;
        const float val = acc[mi][ni][r] + bnv[ni];
        const u16 hi = (u16)(fbits(val) >> 16);
        const u16 lo = (u16)(fbits(bfres(val)) >> 16);
        const size_t base = (size_t)(bb * 16 + hh) << 16;
        if (p == 0)      { Qhi[base + (size_t)l * 64 + hd] = hi;
                           Qlo[base + (size_t)l * 64 + hd] = lo; }
        else if (p == 1) { Khi[base + (size_t)l * 64 + hd] = hi;
                           Klo[base + (size_t)l * 64 + hd] = lo; }
        else             { Vthi[base + (size_t)hd * 1024 + l] = hi;
                           Vtlo[base + (size_t)hd * 1024 + l] = lo; }
      }
    }
  }
}

// ---------------------------------------------------------------------------
// Kernel 4: fused attention v2. 1 l-tile (64 q-rows)/block, 4 waves (lh,rh),
// 65 KB LDS -> 2 blocks/CU. All staging via swizzled global_load_lds.
// Band bias via sheared scatter: VU[l][r]=q_l.e_{l-r+63}, VW[l][r]=k_r.e_{l-r+63}.
// ---------------------------------------------------------------------------
#define KHI_OFF 0
#define KLO_OFF 8192
#define VTHI_OFF 16384
#define VTLO_OFF 24576
#define EB_OFF  32768
#define VU_OFF  49152
#define VW_OFF  58000
#define SM_SIZE 66848

__global__ __launch_bounds__(256) void attn2_kernel(
    const u16* __restrict__ Qhi, const u16* __restrict__ Qlo,
    const u16* __restrict__ Khi, const u16* __restrict__ Klo,
    const u16* __restrict__ Vthi, const u16* __restrict__ Vtlo,
    const u16* __restrict__ embh, const float* __restrict__ mask,
    float* __restrict__ out) {
  __shared__ __align__(16) char sm[SM_SIZE];
  char* KHIb = sm + KHI_OFF;
  char* KLOb = sm + KLO_OFF;
  char* VTHIb = sm + VTHI_OFF;
  char* VTLOb = sm + VTLO_OFF;
  char* EBb  = sm + EB_OFF;
  u16*  VU16 = (u16*)(sm + VU_OFF);   // [65][68], row 64 = trash
  u16*  VW16 = (u16*)(sm + VW_OFF);

  const int tid = threadIdx.x;
  const int lane = tid & 63;
  const int wv = tid >> 6;
  const int lh = wv >> 1, rh = wv & 1;
  const int l15 = lane & 15, g = lane >> 4;

  const int bid = (blockIdx.x & 7) * 128 + (blockIdx.x >> 3);  // XCD swizzle
  const int lt = bid & 15, h = (bid >> 4) & 15, b = bid >> 8;
  const int l0 = lt * 64;
  const size_t bh = (size_t)(b * H_ + h) << 16;
  const float* maskp = mask + b * L_;

  const int scol = ((lane & 7) ^ (lane >> 3)) << 3;  // swizzled source col (elems)
  const int rsub = lane >> 3;

  // ---- prologue: stage Q hi/lo into KHI/KLO, read persistent frags ----
#pragma unroll
  for (int s = 0; s < 4; ++s) {
    int q = wv * 4 + s;
    int buf = q >> 3, rowg = q & 7;
    int row = rowg * 8 + rsub;
    const u16* src = (buf ? Qlo : Qhi) + bh + (size_t)(l0 + row) * 64 + scol;
    gload16(src, (buf ? KLOb : KHIb) + rowg * 1024);
  }
  __syncthreads();

  short8_t qfh[2][2], qfl[2][2];
#pragma unroll
  for (int nb = 0; nb < 2; ++nb)
#pragma unroll
    for (int kc = 0; kc < 2; ++kc) {
      qfh[nb][kc] = ldsfrag(KHIb, 32 * lh + 16 * nb + l15, 64 * kc + 8 * g);
      qfl[nb][kc] = ldsfrag(KLOb, 32 * lh + 16 * nb + l15, 64 * kc + 8 * g);
    }

  f4 o_acc[4][2];
#pragma unroll
  for (int i = 0; i < 4; ++i)
#pragma unroll
    for (int j = 0; j < 2; ++j) o_acc[i][j] = f4{0.f, 0.f, 0.f, 0.f};
  float mrun[2] = {-3e38f, -3e38f};
  float lsum[2] = {0.f, 0.f};

#pragma unroll 1
  for (int rt = 0; rt < 16; ++rt) {
    const int r0 = rt * 64;
    const int dmin = l0 - r0 + 960;
    __syncthreads();  // all reads of K/V/E/VU/VW (and Q prologue) done

    // ---- stage K,V^T,E (12 gload16 per wave) ----
#pragma unroll
    for (int s = 0; s < 12; ++s) {
      int q = wv * 12 + s;
      if (q < 32) {
        int buf = q >> 3, rowg = q & 7;
        int row = rowg * 8 + rsub;
        const u16* src;
        if (buf == 0)      src = Khi + bh + (size_t)(r0 + row) * 64 + scol;
        else if (buf == 1) src = Klo + bh + (size_t)(r0 + row) * 64 + scol;
        else if (buf == 2) src = Vthi + bh + (size_t)row * 1024 + r0 + scol;
        else               src = Vtlo + bh + (size_t)row * 1024 + r0 + scol;
        gload16(src, sm + buf * 8192 + rowg * 1024);
      } else {
        int rowg = q - 32;
        int rowa = rowg * 8 + rsub;
        int srow = dmin + rowa;
        srow = srow < 0 ? 0 : (srow > 2046 ? 2046 : srow);
        gload16(embh + (size_t)srow * 64 + scol, EBb + rowg * 1024);
      }
    }
    __syncthreads();  // staged (barrier drains vmcnt)

    // ---- QK: S^T = K*Q^T (bf16x3) ----
    f4 sacc[2][2];
#pragma unroll
    for (int i = 0; i < 2; ++i)
#pragma unroll
      for (int j = 0; j < 2; ++j) sacc[i][j] = f4{0.f, 0.f, 0.f, 0.f};
    short8_t khf[2][2];
#pragma unroll
    for (int mb = 0; mb < 2; ++mb)
#pragma unroll
      for (int kc = 0; kc < 2; ++kc) {
        short8_t ka = ldsfrag(KHIb, 32 * rh + 16 * mb + l15, 64 * kc + 8 * g);
        short8_t kl = ldsfrag(KLOb, 32 * rh + 16 * mb + l15, 64 * kc + 8 * g);
        khf[mb][kc] = ka;
#pragma unroll
        for (int nb = 0; nb < 2; ++nb) {
          sacc[mb][nb] = MF(ka, qfh[nb][kc], sacc[mb][nb]);
          sacc[mb][nb] = MF(ka, qfl[nb][kc], sacc[mb][nb]);
          sacc[mb][nb] = MF(kl, qfh[nb][kc], sacc[mb][nb]);
        }
      }

    // ---- U2 = Q*E^T, sheared scatter into VU[l][r] (r = l-d+63) ----
#pragma unroll
    for (int dd = 0; dd < 4; ++dd) {
      const int dblk = 64 * rh + 16 * dd;
      const bool v0 = (dblk >= 32 * lh - 15)      && (dblk <= 32 * lh + 78);
      const bool v1 = (dblk >= 32 * lh + 16 - 15) && (dblk <= 32 * lh + 16 + 78);
      if (v0 | v1) {
        f4 u0 = f4{0.f, 0.f, 0.f, 0.f}, u1 = f4{0.f, 0.f, 0.f, 0.f};
#pragma unroll
        for (int kc = 0; kc < 2; ++kc) {
          short8_t eb = ldsfrag(EBb, dblk + l15, 64 * kc + 8 * g);
          if (v0) u0 = MF(qfh[0][kc], eb, u0);
          if (v1) u1 = MF(qfh[1][kc], eb, u1);
        }
        const int dL = dblk + l15;
#pragma unroll
        for (int nb = 0; nb < 2; ++nb) {
          if (nb ? v1 : v0) {
            const f4 uu = nb ? u1 : u0;
            const int lb = 32 * lh + 16 * nb;
#pragma unroll
            for (int j = 0; j < 4; ++j) {
              const int l = lb + 4 * g + j;
              const int r = l - dL + 63;
              const int a = ((unsigned)r < 64u) ? (l * 68 + r) : (4352 + lane);
              VU16[a] = (u16)(fbits(uu[j]) >> 16);
            }
          }
        }
      }
    }

    // ---- W2 = K*E^T, sheared scatter into VW[l][r] (l = r+d-63) ----
#pragma unroll
    for (int dd = 0; dd < 4; ++dd) {
      const int dblk = 64 * lh + 16 * dd;
      const bool w0 = (dblk >= 33 - 32 * rh)        && (dblk <= 126 - 32 * rh);
      const bool w1 = (dblk >= 33 - (32 * rh + 16)) && (dblk <= 126 - (32 * rh + 16));
      if (w0 | w1) {
        f4 wa0 = f4{0.f, 0.f, 0.f, 0.f}, wa1 = f4{0.f, 0.f, 0.f, 0.f};
#pragma unroll
        for (int kc = 0; kc < 2; ++kc) {
          short8_t eb = ldsfrag(EBb, dblk + l15, 64 * kc + 8 * g);
          if (w0) wa0 = MF(khf[0][kc], eb, wa0);
          if (w1) wa1 = MF(khf[1][kc], eb, wa1);
        }
        const int dL = dblk + l15;
#pragma unroll
        for (int mb = 0; mb < 2; ++mb) {
          if (mb ? w1 : w0) {
            const f4 ww = mb ? wa1 : wa0;
            const int rb = 32 * rh + 16 * mb;
#pragma unroll
            for (int j = 0; j < 4; ++j) {
              const int r = rb + 4 * g + j;
              const int l = r + dL - 63;
              const int a = ((unsigned)l < 64u) ? (l * 68 + r) : (4352 + lane);
              VW16[a] = (u16)(fbits(ww[j]) >> 16);
            }
          }
        }
      }
    }
    __syncthreads();  // VU/VW visible

    // ---- assembly + online softmax (per-wave rh chain) ----
    float pbuf[2][2][4];
#pragma unroll
    for (int nb = 0; nb < 2; ++nb) {
      const int lA = 32 * lh + 16 * nb + l15;
      float sv[2][4];
      float ml = -3e38f;
#pragma unroll
      for (int mb = 0; mb < 2; ++mb) {
        const int rr = 32 * rh + 16 * mb + 4 * g;
        const float4 mk = *(const float4*)&maskp[r0 + rr];
        const float mka[4] = {mk.x, mk.y, mk.z, mk.w};
        const short4_t vu = *(const short4_t*)(VU16 + lA * 68 + rr);
        const short4_t vw = *(const short4_t*)(VW16 + lA * 68 + rr);
#pragma unroll
        for (int j = 0; j < 4; ++j) {
          float s = (sacc[mb][nb][j] + bf2f((u16)vu[j]) + bf2f((u16)vw[j])) * 0.125f
                    + mka[j];
          sv[mb][j] = s;
          ml = fmaxf(ml, s);
        }
      }
      ml = fmaxf(ml, __shfl_xor(ml, 16));
      ml = fmaxf(ml, __shfl_xor(ml, 32));
      const float mn = fmaxf(mrun[nb], ml);
      const float rs = __expf(mrun[nb] - mn);
      float ps = 0.f;
#pragma unroll
      for (int mb = 0; mb < 2; ++mb)
#pragma unroll
        for (int j = 0; j < 4; ++j) {
          const float pv = __expf(sv[mb][j] - mn);
          pbuf[nb][mb][j] = pv;
          ps += pv;
        }
      ps += __shfl_xor(ps, 16);
      ps += __shfl_xor(ps, 32);
      lsum[nb] = lsum[nb] * rs + ps;
      mrun[nb] = mn;
#pragma unroll
      for (int mbd = 0; mbd < 4; ++mbd) {
        o_acc[mbd][nb][0] *= rs; o_acc[mbd][nb][1] *= rs;
        o_acc[mbd][nb][2] *= rs; o_acc[mbd][nb][3] *= rs;
      }
    }

    // ---- P fragments (hi/lo) from registers ----
    short8_t pf[2], pl_[2];
#pragma unroll
    for (int nb = 0; nb < 2; ++nb) {
      union { unsigned u[4]; short8_t v; } uh, ul;
      uh.u[0] = pack2hi(pbuf[nb][0][0], pbuf[nb][0][1]);
      uh.u[1] = pack2hi(pbuf[nb][0][2], pbuf[nb][0][3]);
      uh.u[2] = pack2hi(pbuf[nb][1][0], pbuf[nb][1][1]);
      uh.u[3] = pack2hi(pbuf[nb][1][2], pbuf[nb][1][3]);
      pf[nb] = uh.v;
      ul.u[0] = pack2hi(bfres(pbuf[nb][0][0]), bfres(pbuf[nb][0][1]));
      ul.u[1] = pack2hi(bfres(pbuf[nb][0][2]), bfres(pbuf[nb][0][3]));
      ul.u[2] = pack2hi(bfres(pbuf[nb][1][0]), bfres(pbuf[nb][1][1]));
      ul.u[3] = pack2hi(bfres(pbuf[nb][1][2]), bfres(pbuf[nb][1][3]));
      pl_[nb] = ul.v;
    }

    // ---- PV: O^T += V^T * P^T (bf16x3) ----
#pragma unroll
    for (int mbd = 0; mbd < 4; ++mbd) {
      short8_t vh = ldsfrag(VTHIb, 16 * mbd + l15, 64 * rh + 8 * g);
      short8_t vl = ldsfrag(VTLOb, 16 * mbd + l15, 64 * rh + 8 * g);
#pragma unroll
      for (int nb = 0; nb < 2; ++nb) {
        o_acc[mbd][nb] = MF(vh, pf[nb], o_acc[mbd][nb]);
        o_acc[mbd][nb] = MF(vh, pl_[nb], o_acc[mbd][nb]);
        o_acc[mbd][nb] = MF(vl, pf[nb], o_acc[mbd][nb]);
      }
    }
  }

  // ---- epilogue: merge the two rh chains (partner wave wv^1), store ----
  __syncthreads();
  float* mbuf = (float*)EBb;
  float* obuf = (float*)(sm + VU_OFF);   // [64][65] f32
  if (g == 0) {
#pragma unroll
    for (int nb = 0; nb < 2; ++nb) {
      mbuf[((wv * 2 + nb) * 16 + l15) * 2 + 0] = mrun[nb];
      mbuf[((wv * 2 + nb) * 16 + l15) * 2 + 1] = lsum[nb];
    }
  }
  __syncthreads();
  const int pw = wv ^ 1;
  float alpha[2], ltot[2];
#pragma unroll
  for (int nb = 0; nb < 2; ++nb) {
    float m2 = mbuf[((pw * 2 + nb) * 16 + l15) * 2 + 0];
    float s2 = mbuf[((pw * 2 + nb) * 16 + l15) * 2 + 1];
    float M = fmaxf(mrun[nb], m2);
    alpha[nb] = __expf(mrun[nb] - M);
    ltot[nb] = lsum[nb] * alpha[nb] + s2 * __expf(m2 - M);
  }
  if (rh == 1) {
#pragma unroll
    for (int mbd = 0; mbd < 4; ++mbd)
#pragma unroll
      for (int nb = 0; nb < 2; ++nb)
#pragma unroll
        for (int j = 0; j < 4; ++j)
          obuf[(16 * mbd + 4 * g + j) * 65 + 32 * lh + 16 * nb + l15] =
              o_acc[mbd][nb][j] * alpha[nb];
  }
  __syncthreads();
  if (rh == 0) {
#pragma unroll
    for (int mbd = 0; mbd < 4; ++mbd)
#pragma unroll
      for (int nb = 0; nb < 2; ++nb) {
        const int lgl = l0 + 32 * lh + 16 * nb + l15;
        const float inv = 1.f / ltot[nb];
        float tmp[4];
#pragma unroll
        for (int j = 0; j < 4; ++j)
          tmp[j] = (o_acc[mbd][nb][j] * alpha[nb] +
                    obuf[(16 * mbd + 4 * g + j) * 65 + 32 * lh + 16 * nb + l15]) * inv;
        float4 ov; ov.x = tmp[0]; ov.y = tmp[1]; ov.z = tmp[2]; ov.w = tmp[3];
        *(float4*)&out[(size_t)(b * L_ + lgl) * D_ + h * HD_ + 16 * mbd + 4 * g] = ov;
      }
  }
}

// ---------------------------------------------------------------------------
extern "C" void kernel_launch(void* const* d_in, const int* in_sizes, int n_in,
                              void* d_out, int out_size, void* d_ws, size_t ws_size,
                              hipStream_t stream) {
  const float* hs   = (const float*)d_in[0];
  const float* mask = (const float*)d_in[1];
  const float* tw   = (const float*)d_in[2];
  const float* wlw  = (const float*)d_in[3];
  const float* scw  = (const float*)d_in[4];
  const float* shw  = (const float*)d_in[5];
  const float* tb   = (const float*)d_in[6];
  const float* wlb  = (const float*)d_in[7];
  const float* scb  = (const float*)d_in[8];
  const float* shb  = (const float*)d_in[9];
  const float* emb  = (const float*)d_in[10];
  float* out = (float*)d_out;

  char* W = (char*)d_ws;
  float* b_s = (float*)W;                         // 3072 f32
  u16* whi  = (u16*)(W + 12288);                  // 3*2^20
  u16* wlo  = whi + 3145728;
  u16* embh = wlo + 3145728;                      // 131008 (pad to 131072)
  u16* Qhi  = embh + 131072;                      // planes: 4*2^20 each
  u16* Qlo  = Qhi + 4194304;
  u16* Khi  = Qlo + 4194304;
  u16* Klo  = Khi + 4194304;
  u16* Vthi = Klo + 4194304;
  u16* Vtlo = Vthi + 4194304;                     // total ~63.2 MB

  hipLaunchKernelGGL(wgen_kernel, dim3(3072), dim3(256), 0, stream,
                     tw, wlw, scw, shw, whi, wlo);
  hipLaunchKernelGGL(bgen_kernel, dim3(12), dim3(256), 0, stream,
                     tb, wlb, scb, shb, b_s);
  hipLaunchKernelGGL(ecvt_kernel, dim3(128), dim3(256), 0, stream, emb, embh);
  hipLaunchKernelGGL(proj_mfma_kernel, dim3(768), dim3(256), 0, stream,
                     hs, whi, wlo, b_s, Qhi, Qlo, Khi, Klo, Vthi, Vtlo);
  hipLaunchKernelGGL(attn2_kernel, dim3(1024), dim3(256), 0, stream,
                     Qhi, Qlo, Khi, Klo, Vthi, Vtlo, embh, mask, out);
}

// Round 5
// 383.520 us; speedup vs baseline: 1.2254x; 1.2254x over previous
//
#include <hip/hip_runtime.h>
#include <hip/hip_bf16.h>
#include <math.h>

#define D_  1024
#define L_  1024
#define B_  4
#define H_  16
#define HD_ 64

typedef __attribute__((ext_vector_type(4))) short short4_t;
typedef __attribute__((ext_vector_type(8))) short short8_t;
typedef __attribute__((ext_vector_type(4))) float f4;
typedef unsigned short u16;

__device__ __forceinline__ f4 MF(short8_t a, short8_t b, f4 c) {
  return __builtin_amdgcn_mfma_f32_16x16x32_bf16(a, b, c, 0, 0, 0);
}
__device__ __forceinline__ unsigned fbits(float x) { return __builtin_bit_cast(unsigned, x); }
__device__ __forceinline__ float bf2f(unsigned short u) {
  return __builtin_bit_cast(float, (unsigned)u << 16);
}
__device__ __forceinline__ unsigned pack2hi(float x, float y) {
  return (fbits(x) >> 16) | (fbits(y) & 0xFFFF0000u);
}
__device__ __forceinline__ float bfres(float x) {  // x - trunc_bf16(x)
  return x - __builtin_bit_cast(float, fbits(x) & 0xFFFF0000u);
}
__device__ __forceinline__ void gload16(const void* g, void* l) {
  __builtin_amdgcn_global_load_lds(
      (const __attribute__((address_space(1))) unsigned*)g,
      (__attribute__((address_space(3))) unsigned*)l, 16, 0, 0);
}
// two b64 reads forming one MFMA frag; 128B rows, XOR-swizzled (involution,
// matches the gload16 source-side swizzle scol = ((lane&7)^(lane>>3))<<3)
__device__ __forceinline__ short8_t ldsfrag(const char* base, int row, int cb) {
  const char* p = base + row * 128;
  const int sw = (row & 7) << 4;
  union { short4_t q[2]; short8_t v; } u;
  u.q[0] = *(const short4_t*)(p + (cb ^ sw));
  u.q[1] = *(const short4_t*)(p + ((cb + 32) ^ sw));
  return u.v;
}

// ---------------------------------------------------------------------------
// Kernel 1: student weight generation -> bf16 hi/lo planes, K-permuted
// (within each 32-col block, k-quad q -> pos (q&3)*8+((q>>2)&1)*4 so one b128
//  at [row][8g] is a complete MFMA fragment).
// ---------------------------------------------------------------------------
__global__ __launch_bounds__(256) void wgen_kernel(
    const float* __restrict__ tw, const float* __restrict__ wl,
    const float* __restrict__ sc, const float* __restrict__ sh,
    u16* __restrict__ whi, u16* __restrict__ wlo) {
  size_t i4 = (size_t)blockIdx.x * 256 + threadIdx.x;
  size_t e = i4 * 4;
  int p = (int)(e >> 20);
  size_t rem = e & 0xFFFFFu;
  float a0 = wl[p * 2 + 0], a1 = wl[p * 2 + 1];
  float4 t0 = *(const float4*)&tw[((size_t)(p * 2 + 0) << 20) + rem];
  float4 t1 = *(const float4*)&tw[((size_t)(p * 2 + 1) << 20) + rem];
  float4 s4 = *(const float4*)&sc[e];
  float4 h4 = *(const float4*)&sh[e];
  float4 o;
  o.x = tanhf(a0 * t0.x + a1 * t1.x) * s4.x + h4.x;
  o.y = tanhf(a0 * t0.y + a1 * t1.y) * s4.y + h4.y;
  o.z = tanhf(a0 * t0.z + a1 * t1.z) * s4.z + h4.z;
  o.w = tanhf(a0 * t0.w + a1 * t1.w) * s4.w + h4.w;
  const int q = (int)((e & 1023) >> 2);
  const size_t off = (e & ~(size_t)1023) +
                     (q >> 3) * 32 + (q & 3) * 8 + ((q >> 2) & 1) * 4;
  uint2 hi; hi.x = pack2hi(o.x, o.y); hi.y = pack2hi(o.z, o.w);
  *(uint2*)&whi[off] = hi;
  uint2 lo; lo.x = pack2hi(bfres(o.x), bfres(o.y)); lo.y = pack2hi(bfres(o.z), bfres(o.w));
  *(uint2*)&wlo[off] = lo;
}

// ---------------------------------------------------------------------------
// Kernel 2: bias generation (f32)
// ---------------------------------------------------------------------------
__global__ __launch_bounds__(256) void bgen_kernel(
    const float* __restrict__ tb, const float* __restrict__ wl,
    const float* __restrict__ sc, const float* __restrict__ sh,
    float* __restrict__ b_out) {
  int i = blockIdx.x * 256 + threadIdx.x;
  int p = i >> 10;
  int o = i & 1023;
  float v = tanhf(wl[p * 2 + 0] * tb[(p * 2 + 0) * D_ + o] +
                  wl[p * 2 + 1] * tb[(p * 2 + 1) * D_ + o]);
  b_out[i] = v * sc[i] + sh[i];
}

// ---------------------------------------------------------------------------
// Kernel 2b: dist_emb f32 -> bf16 (row-major; row 2047 left as-is/unused)
// ---------------------------------------------------------------------------
__global__ __launch_bounds__(256) void ecvt_kernel(
    const float* __restrict__ emb, u16* __restrict__ embh) {
  int i4 = blockIdx.x * 256 + threadIdx.x;
  if (i4 >= 32752) return;   // 2047*64/4
  int e = i4 * 4;
  float4 v = *(const float4*)&emb[e];
  uint2 h2; h2.x = pack2hi(v.x, v.y); h2.y = pack2hi(v.z, v.w);
  *(uint2*)&embh[e] = h2;
}

// ---------------------------------------------------------------------------
// Kernel 3: QKV projection, bf16x3 MFMA; writes six bf16 planes:
// Qhi/Qlo, Khi/Klo as [b*16+h][l][hd]; Vthi/Vtlo TRANSPOSED [b*16+h][hd][l].
// Epilogue transposes through LDS for coalesced uint2 stores.
// ---------------------------------------------------------------------------
__global__ __launch_bounds__(256) void proj_mfma_kernel(
    const float* __restrict__ hs,
    const u16* __restrict__ Bhp, const u16* __restrict__ Blp,
    const float* __restrict__ bias,
    u16* __restrict__ Qhi, u16* __restrict__ Qlo,
    u16* __restrict__ Khi, u16* __restrict__ Klo,
    u16* __restrict__ Vthi, u16* __restrict__ Vtlo) {
  __shared__ u16 Ah[128][32], Al[128][32], Bh[128][32], Bl[128][32];
  const int tid  = threadIdx.x;
  const int lane = tid & 63;
  const int wv   = tid >> 6;
  const int wm   = wv >> 1, wn = wv & 1;
  const int l15  = lane & 15, g = lane >> 4;

  const int bid = (blockIdx.x & 7) * 96 + (blockIdx.x >> 3);  // XCD swizzle
  const int mt = bid & 31, nt = bid >> 5;
  const int m0 = mt * 128, n0 = nt * 128;

  f4 acc[4][4];
#pragma unroll
  for (int i = 0; i < 4; ++i)
#pragma unroll
    for (int j = 0; j < 4; ++j) acc[i][j] = f4{0.f, 0.f, 0.f, 0.f};

#pragma unroll 1
  for (int k0 = 0; k0 < D_; k0 += 32) {
#pragma unroll
    for (int s = 0; s < 4; ++s) {
      int q = wv * 4 + s;
      int plane = q >> 3, rowg = q & 7;
      const u16* src = (plane ? Blp : Bhp) +
                       (size_t)(n0 + rowg * 16 + (lane >> 2)) * 1024 + k0 + (lane & 3) * 8;
      u16* dst = (plane ? &Bl[0][0] : &Bh[0][0]) + rowg * 512;
      gload16(src, dst);
    }
#pragma unroll
    for (int c = 0; c < 4; ++c) {
      int f4id = tid + c * 256;
      int row = f4id >> 3, q4 = f4id & 7;
      float4 v = *(const float4*)&hs[(size_t)(m0 + row) * 1024 + k0 + q4 * 4];
      int col = (q4 & 3) * 8 + ((q4 >> 2) & 1) * 4;
      uint2 hi2; hi2.x = pack2hi(v.x, v.y); hi2.y = pack2hi(v.z, v.w);
      *(uint2*)&Ah[row][col] = hi2;
      uint2 lo2; lo2.x = pack2hi(bfres(v.x), bfres(v.y)); lo2.y = pack2hi(bfres(v.z), bfres(v.w));
      *(uint2*)&Al[row][col] = lo2;
    }
    __syncthreads();

    short8_t ah[4], al[4], bh[4], bl[4];
#pragma unroll
    for (int i = 0; i < 4; ++i) {
      ah[i] = *(const short8_t*)&Ah[wm * 64 + i * 16 + l15][g * 8];
      al[i] = *(const short8_t*)&Al[wm * 64 + i * 16 + l15][g * 8];
      bh[i] = *(const short8_t*)&Bh[wn * 64 + i * 16 + l15][g * 8];
      bl[i] = *(const short8_t*)&Bl[wn * 64 + i * 16 + l15][g * 8];
    }
#pragma unroll
    for (int mi = 0; mi < 4; ++mi)
#pragma unroll
      for (int ni = 0; ni < 4; ++ni) {
        acc[mi][ni] = MF(ah[mi], bh[ni], acc[mi][ni]);
        acc[mi][ni] = MF(ah[mi], bl[ni], acc[mi][ni]);
        acc[mi][ni] = MF(al[mi], bh[ni], acc[mi][ni]);
      }
    __syncthreads();
  }

  // ---- epilogue: per-mi LDS transpose -> coalesced uint2 plane stores ----
  const int p = n0 >> 10;
  const int h0 = (n0 >> 6) & 15;
  const int nbase = n0 + wn * 64;
  float bnv[4];
#pragma unroll
  for (int ni = 0; ni < 4; ++ni) bnv[ni] = bias[nbase + ni * 16 + l15];
  float* T = (float*)&Ah[0][0];   // 32 x 132 f32 = 16896 B (fits in 32 KB)

#pragma unroll
  for (int mi = 0; mi < 4; ++mi) {
    __syncthreads();
#pragma unroll
    for (int ni = 0; ni < 4; ++ni)
#pragma unroll
      for (int r = 0; r < 4; ++r)
        T[(wm * 16 + 4 * g + r) * 132 + wn * 64 + ni * 16 + l15] =
            acc[mi][ni][r] + bnv[ni];
    __syncthreads();

    if (p < 2) {
      u16* PH = p ? Khi : Qhi;
      u16* PL = p ? Klo : Qlo;
      const int lr = tid >> 3;
      const int m = m0 + (lr >> 4) * 64 + mi * 16 + (lr & 15);
      const int bb = m >> 10, l = m & 1023;
#pragma unroll
      for (int c = 0; c < 4; ++c) {
        const int col = 4 * (tid & 7) + 32 * c;
        const int hd = col & 63, hl = col >> 6;
        float4 v = *(const float4*)&T[lr * 132 + col];
        uint2 hi; hi.x = pack2hi(v.x, v.y); hi.y = pack2hi(v.z, v.w);
        uint2 lo; lo.x = pack2hi(bfres(v.x), bfres(v.y)); lo.y = pack2hi(bfres(v.z), bfres(v.w));
        const size_t ad = ((size_t)(bb * 16 + h0 + hl) << 16) + (size_t)l * 64 + hd;
        *(uint2*)&PH[ad] = hi;
        *(uint2*)&PL[ad] = lo;
      }
    } else {
      const int col = (tid >> 3) & 31;  // with +32c covers 0..127
#pragma unroll
      for (int c = 0; c < 4; ++c) {
        const int cc = col + 32 * c;
        const int hd = cc & 63, hl = cc >> 6;
        const int mq = tid & 7;
        const int lr0 = 4 * mq;
        float vv[4];
#pragma unroll
        for (int k = 0; k < 4; ++k) vv[k] = T[(lr0 + k) * 132 + cc];
        const int m = m0 + (lr0 >> 4) * 64 + mi * 16 + (lr0 & 15);
        const int bb = m >> 10, l = m & 1023;
        uint2 hi; hi.x = pack2hi(vv[0], vv[1]); hi.y = pack2hi(vv[2], vv[3]);
        uint2 lo; lo.x = pack2hi(bfres(vv[0]), bfres(vv[1]));
        lo.y = pack2hi(bfres(vv[2]), bfres(vv[3]));
        const size_t ad = ((size_t)(bb * 16 + h0 + hl) << 16) + (size_t)hd * 1024 + l;
        *(uint2*)&Vthi[ad] = hi;
        *(uint2*)&Vtlo[ad] = lo;
      }
    }
  }
}

// ---------------------------------------------------------------------------
// Kernel 4: fused attention v3.
// 512 thr / 8 waves: wv = (t, lh, rh). 2 l-tiles of 64 per block, grid 512.
// K/V double-buffered, E 256-row ring, staging via swizzled global_load_lds
// issued at iter start (drained by NEXT iter's barrier -> latency hidden).
// Position bias: U[l][r]=q_l.e_d, W[l][r]=k_r.e_d (d=l-r+63 rel) by sheared
// scatter from band GEMMs; balanced db = (2lh+rh) + 4*dd work split.
// ---------------------------------------------------------------------------
#define KD_OFF 0
#define VD_OFF 32768
#define ER_OFF 65536
#define VU_OFF 98304
#define VW_OFF 115984
#define SM3_SIZE 133664

__global__ __launch_bounds__(512, 2) void attn3_kernel(
    const u16* __restrict__ Qhi, const u16* __restrict__ Qlo,
    const u16* __restrict__ Khi, const u16* __restrict__ Klo,
    const u16* __restrict__ Vthi, const u16* __restrict__ Vtlo,
    const u16* __restrict__ embh, const float* __restrict__ mask,
    float* __restrict__ out) {
  __shared__ __align__(16) char sm[SM3_SIZE];
  char* ERb = sm + ER_OFF;

  const int tid  = threadIdx.x;
  const int lane = tid & 63;
  const int wv   = tid >> 6;
  const int t    = wv >> 2;
  const int lh   = (wv >> 1) & 1;
  const int rh   = wv & 1;
  const int w4   = 2 * lh + rh;
  const int l15  = lane & 15;
  const int g    = lane >> 4;
  const int rsub = lane >> 3;
  const int scol = ((lane & 7) ^ (lane >> 3)) << 3;  // u16 units

  const int bid = (blockIdx.x & 7) * 64 + (blockIdx.x >> 3);  // XCD swizzle
  const int lp = bid & 7, h = (bid >> 3) & 15, b = bid >> 7;
  const int l0 = lp * 128;
  const size_t bhoff = (size_t)(b * 16 + h) << 16;
  const float* maskp = mask + b * L_;

  u16* VUt = (u16*)(sm + VU_OFF) + t * 4420;  // [65][68], row 64 = trash
  u16* VWt = (u16*)(sm + VW_OFF) + t * 4420;

  // ---- prologue: stage Q into ER area, read persistent frags ----
#pragma unroll
  for (int s = 0; s < 4; ++s) {
    const int idx = wv * 4 + s;
    const int plane = idx >> 4, rowg = idx & 15;
    const u16* src = (plane ? Qlo : Qhi) + bhoff +
                     (size_t)(l0 + rowg * 8 + rsub) * 64 + scol;
    gload16(src, ERb + (plane * 16 + rowg) * 1024);
  }
  __syncthreads();

  short8_t qfh[4][2], qfl[4][2];   // [lb of this tile][kc]
#pragma unroll
  for (int lb = 0; lb < 4; ++lb)
#pragma unroll
    for (int kc = 0; kc < 2; ++kc) {
      qfh[lb][kc] = ldsfrag(ERb,         64 * t + 16 * lb + l15, 64 * kc + 8 * g);
      qfl[lb][kc] = ldsfrag(ERb + 16384, 64 * t + 16 * lb + l15, 64 * kc + 8 * g);
    }
  __syncthreads();  // ER free for the E ring

  // ---- stage K/V(0) and E(0) window [dmin0, dmin0+191] ----
  {
#pragma unroll
    for (int s = 0; s < 2; ++s) {
      const int idx = wv * 2 + s;
      const int plane = idx >> 3, rowg = idx & 7;
      const u16* ks = (plane ? Klo : Khi) + bhoff +
                      (size_t)(rowg * 8 + rsub) * 64 + scol;
      gload16(ks, sm + KD_OFF + plane * 8192 + rowg * 1024);
      const u16* vs = (plane ? Vtlo : Vthi) + bhoff +
                      (size_t)(rowg * 8 + rsub) * 1024 + 0 + scol;
      gload16(vs, sm + VD_OFF + plane * 8192 + rowg * 1024);
    }
    const int dmin0 = l0 + 960;
#pragma unroll
    for (int s = 0; s < 3; ++s) {
      const int grp = wv * 3 + s;  // 0..23
      const int slot = ((dmin0 & 255) + grp * 8) & 255;
      gload16(embh + (size_t)(dmin0 + grp * 8 + rsub) * 64 + scol,
              ERb + slot * 128);
    }
  }

  f4 o_acc[4][2];
#pragma unroll
  for (int i = 0; i < 4; ++i)
#pragma unroll
    for (int j = 0; j < 2; ++j) o_acc[i][j] = f4{0.f, 0.f, 0.f, 0.f};
  float mrun[2] = {-3e38f, -3e38f};
  float lsum[2] = {0.f, 0.f};

#pragma unroll 1
  for (int rt = 0; rt < 16; ++rt) {
    const int r0 = rt * 64;
    const int cur = rt & 1;
    const int dmin = l0 - r0 + 960;
    const int dmin_t = dmin + 64 * t;

    __syncthreads();  // drains staging for cur; separates buffer reuse

    // ---- (A) async staging for rt+1 ----
    if (rt < 15) {
      const int r1 = r0 + 64;
      const int nxt = cur ^ 1;
      char* kdn = sm + KD_OFF + nxt * 16384;
      char* vdn = sm + VD_OFF + nxt * 16384;
#pragma unroll
      for (int s = 0; s < 2; ++s) {
        const int idx = wv * 2 + s;
        const int plane = idx >> 3, rowg = idx & 7;
        const u16* ks = (plane ? Klo : Khi) + bhoff +
                        (size_t)(r1 + rowg * 8 + rsub) * 64 + scol;
        gload16(ks, kdn + plane * 8192 + rowg * 1024);
        const u16* vs = (plane ? Vtlo : Vthi) + bhoff +
                        (size_t)(rowg * 8 + rsub) * 1024 + r1 + scol;
        gload16(vs, vdn + plane * 8192 + rowg * 1024);
      }
      const int dminN = dmin - 64;
      const int slot = ((dminN & 255) + wv * 8) & 255;
      gload16(embh + (size_t)(dminN + wv * 8 + rsub) * 64 + scol,
              ERb + slot * 128);
    }

    // mask prefetch
    float4 mk[2];
#pragma unroll
    for (int mb = 0; mb < 2; ++mb)
      mk[mb] = *(const float4*)&maskp[r0 + 32 * rh + 16 * mb + 4 * g];

    const char* kdc_h = sm + KD_OFF + cur * 16384;
    const char* kdc_l = kdc_h + 8192;
    const char* vdc_h = sm + VD_OFF + cur * 16384;
    const char* vdc_l = vdc_h + 8192;

    // ---- (B) QK: S^T = K * Q^T (bf16x3) ----
    f4 sacc[2][2];
#pragma unroll
    for (int i = 0; i < 2; ++i)
#pragma unroll
      for (int j = 0; j < 2; ++j) sacc[i][j] = f4{0.f, 0.f, 0.f, 0.f};
#pragma unroll
    for (int mb = 0; mb < 2; ++mb)
#pragma unroll
      for (int kc = 0; kc < 2; ++kc) {
        short8_t ka = ldsfrag(kdc_h, 32 * rh + 16 * mb + l15, 64 * kc + 8 * g);
        short8_t kl = ldsfrag(kdc_l, 32 * rh + 16 * mb + l15, 64 * kc + 8 * g);
#pragma unroll
        for (int nb = 0; nb < 2; ++nb) {
          const int lb = 2 * lh + nb;
          sacc[mb][nb] = MF(ka, qfh[lb][kc], sacc[mb][nb]);
          sacc[mb][nb] = MF(ka, qfl[lb][kc], sacc[mb][nb]);
          sacc[mb][nb] = MF(kl, qfh[lb][kc], sacc[mb][nb]);
        }
      }

    // ---- (C) U/W band GEMMs with sheared scatter ----
#pragma unroll
    for (int dd = 0; dd < 2; ++dd) {
      const int db = w4 + 4 * dd;
      const int drel = 16 * db + l15;
      const int erow = (dmin_t + 16 * db + l15) & 255;
      const short8_t eb0 = ldsfrag(ERb, erow, 8 * g);
      const short8_t eb1 = ldsfrag(ERb, erow, 64 + 8 * g);
      // U: C[l_loc][drel] = q . e
#pragma unroll
      for (int lb = 0; lb < 4; ++lb) {
        if (db >= lb && db <= lb + 4) {
          f4 u = f4{0.f, 0.f, 0.f, 0.f};
          u = MF(qfh[lb][0], eb0, u);
          u = MF(qfh[lb][1], eb1, u);
#pragma unroll
          for (int j = 0; j < 4; ++j) {
            const int lloc = 16 * lb + 4 * g + j;
            const int rloc = lloc - drel + 63;
            const int a = ((unsigned)rloc < 64u) ? (lloc * 68 + rloc)
                                                 : (64 * 68 + lane);
            VUt[a] = (u16)(fbits(u[j]) >> 16);
          }
        }
      }
      // W: C[r_loc][drel] = k . e, scattered to [l_loc][r_loc]
#pragma unroll
      for (int rb = 0; rb < 4; ++rb) {
        const int sdb = rb + db;
        if (sdb >= 3 && sdb <= 7) {
          short8_t k0 = ldsfrag(kdc_h, 16 * rb + l15, 8 * g);
          short8_t k1 = ldsfrag(kdc_h, 16 * rb + l15, 64 + 8 * g);
          f4 w = f4{0.f, 0.f, 0.f, 0.f};
          w = MF(k0, eb0, w);
          w = MF(k1, eb1, w);
#pragma unroll
          for (int j = 0; j < 4; ++j) {
            const int rloc = 16 * rb + 4 * g + j;
            const int lloc = rloc + drel - 63;
            const int a = ((unsigned)lloc < 64u) ? (lloc * 68 + rloc)
                                                 : (64 * 68 + lane);
            VWt[a] = (u16)(fbits(w[j]) >> 16);
          }
        }
      }
    }
    __syncthreads();  // VU/VW visible

    // ---- (D) assembly + online softmax (per-wave rh chain) ----
    float pbuf[2][2][4];
#pragma unroll
    for (int nb = 0; nb < 2; ++nb) {
      const int lA = 32 * lh + 16 * nb + l15;
      float sv[2][4];
      float ml = -3e38f;
#pragma unroll
      for (int mb = 0; mb < 2; ++mb) {
        const int rr = 32 * rh + 16 * mb + 4 * g;
        const float mka[4] = {mk[mb].x, mk[mb].y, mk[mb].z, mk[mb].w};
        const short4_t vu = *(const short4_t*)(VUt + lA * 68 + rr);
        const short4_t vw = *(const short4_t*)(VWt + lA * 68 + rr);
#pragma unroll
        for (int j = 0; j < 4; ++j) {
          float s = (sacc[mb][nb][j] + bf2f((u16)vu[j]) + bf2f((u16)vw[j])) * 0.125f
                    + mka[j];
          sv[mb][j] = s;
          ml = fmaxf(ml, s);
        }
      }
      ml = fmaxf(ml, __shfl_xor(ml, 16));
      ml = fmaxf(ml, __shfl_xor(ml, 32));
      const float mn = fmaxf(mrun[nb], ml);
      const float rs = __expf(mrun[nb] - mn);
      float ps = 0.f;
#pragma unroll
      for (int mb = 0; mb < 2; ++mb)
#pragma unroll
        for (int j = 0; j < 4; ++j) {
          const float pv = __expf(sv[mb][j] - mn);
          pbuf[nb][mb][j] = pv;
          ps += pv;
        }
      ps += __shfl_xor(ps, 16);
      ps += __shfl_xor(ps, 32);
      lsum[nb] = lsum[nb] * rs + ps;
      mrun[nb] = mn;
#pragma unroll
      for (int mbd = 0; mbd < 4; ++mbd) {
        o_acc[mbd][nb][0] *= rs; o_acc[mbd][nb][1] *= rs;
        o_acc[mbd][nb][2] *= rs; o_acc[mbd][nb][3] *= rs;
      }
    }

    // ---- (E) P fragments (hi/lo) from registers; PV ----
    short8_t pf[2], pl_[2];
#pragma unroll
    for (int nb = 0; nb < 2; ++nb) {
      union { unsigned u[4]; short8_t v; } uh, ul;
      uh.u[0] = pack2hi(pbuf[nb][0][0], pbuf[nb][0][1]);
      uh.u[1] = pack2hi(pbuf[nb][0][2], pbuf[nb][0][3]);
      uh.u[2] = pack2hi(pbuf[nb][1][0], pbuf[nb][1][1]);
      uh.u[3] = pack2hi(pbuf[nb][1][2], pbuf[nb][1][3]);
      pf[nb] = uh.v;
      ul.u[0] = pack2hi(bfres(pbuf[nb][0][0]), bfres(pbuf[nb][0][1]));
      ul.u[1] = pack2hi(bfres(pbuf[nb][0][2]), bfres(pbuf[nb][0][3]));
      ul.u[2] = pack2hi(bfres(pbuf[nb][1][0]), bfres(pbuf[nb][1][1]));
      ul.u[3] = pack2hi(bfres(pbuf[nb][1][2]), bfres(pbuf[nb][1][3]));
      pl_[nb] = ul.v;
    }
#pragma unroll
    for (int mbd = 0; mbd < 4; ++mbd) {
      short8_t vh = ldsfrag(vdc_h, 16 * mbd + l15, 64 * rh + 8 * g);
      short8_t vl = ldsfrag(vdc_l, 16 * mbd + l15, 64 * rh + 8 * g);
#pragma unroll
      for (int nb = 0; nb < 2; ++nb) {
        o_acc[mbd][nb] = MF(vh, pf[nb], o_acc[mbd][nb]);
        o_acc[mbd][nb] = MF(vh, pl_[nb], o_acc[mbd][nb]);
        o_acc[mbd][nb] = MF(vl, pf[nb], o_acc[mbd][nb]);
      }
    }
  }

  // ---- epilogue: merge the two rh chains (partner wave wv^1), store ----
  __syncthreads();
  float* mbuf = (float*)ERb;
  float* obuf = (float*)(sm + VU_OFF);   // [256][32] f32 = 32 KB
  if (g == 0) {
#pragma unroll
    for (int nb = 0; nb < 2; ++nb) {
      mbuf[((wv * 2 + nb) * 16 + l15) * 2 + 0] = mrun[nb];
      mbuf[((wv * 2 + nb) * 16 + l15) * 2 + 1] = lsum[nb];
    }
  }
  __syncthreads();
  const int pw = wv ^ 1;
  float alpha[2], ltot[2];
#pragma unroll
  for (int nb = 0; nb < 2; ++nb) {
    float m2 = mbuf[((pw * 2 + nb) * 16 + l15) * 2 + 0];
    float s2 = mbuf[((pw * 2 + nb) * 16 + l15) * 2 + 1];
    float M = fmaxf(mrun[nb], m2);
    alpha[nb] = __expf(mrun[nb] - M);
    ltot[nb] = lsum[nb] * alpha[nb] + s2 * __expf(m2 - M);
  }
  const int pair = wv >> 1;   // (t, lh)
  if (rh == 1) {
#pragma unroll
    for (int mbd = 0; mbd < 4; ++mbd)
#pragma unroll
      for (int nb = 0; nb < 2; ++nb)
#pragma unroll
        for (int j = 0; j < 4; ++j)
          obuf[(pair * 64 + 16 * mbd + 4 * g + j) * 32 + 16 * nb + l15] =
              o_acc[mbd][nb][j] * alpha[nb];
  }
  __syncthreads();
  if (rh == 0) {
#pragma unroll
    for (int mbd = 0; mbd < 4; ++mbd)
#pragma unroll
      for (int nb = 0; nb < 2; ++nb) {
        const int lgl = l0 + 64 * t + 32 * lh + 16 * nb + l15;
        const float inv = 1.f / ltot[nb];
        float tmp[4];
#pragma unroll
        for (int j = 0; j < 4; ++j)
          tmp[j] = (o_acc[mbd][nb][j] * alpha[nb] +
                    obuf[(pair * 64 + 16 * mbd + 4 * g + j) * 32 + 16 * nb + l15]) * inv;
        float4 ov; ov.x = tmp[0]; ov.y = tmp[1]; ov.z = tmp[2]; ov.w = tmp[3];
        *(float4*)&out[(size_t)(b * L_ + lgl) * D_ + h * HD_ + 16 * mbd + 4 * g] = ov;
      }
  }
}

// ---------------------------------------------------------------------------
extern "C" void kernel_launch(void* const* d_in, const int* in_sizes, int n_in,
                              void* d_out, int out_size, void* d_ws, size_t ws_size,
                              hipStream_t stream) {
  const float* hs   = (const float*)d_in[0];
  const float* mask = (const float*)d_in[1];
  const float* tw   = (const float*)d_in[2];
  const float* wlw  = (const float*)d_in[3];
  const float* scw  = (const float*)d_in[4];
  const float* shw  = (const float*)d_in[5];
  const float* tb   = (const float*)d_in[6];
  const float* wlb  = (const float*)d_in[7];
  const float* scb  = (const float*)d_in[8];
  const float* shb  = (const float*)d_in[9];
  const float* emb  = (const float*)d_in[10];
  float* out = (float*)d_out;

  char* W = (char*)d_ws;
  float* b_s = (float*)W;                         // 3072 f32
  u16* whi  = (u16*)(W + 12288);
  u16* wlo  = whi + 3145728;
  u16* embh = wlo + 3145728;                      // 2048 rows x 64 (row 2047 pad)
  u16* Qhi  = embh + 131072;
  u16* Qlo  = Qhi + 4194304;
  u16* Khi  = Qlo + 4194304;
  u16* Klo  = Khi + 4194304;
  u16* Vthi = Klo + 4194304;
  u16* Vtlo = Vthi + 4194304;                     // total ~63 MB

  hipLaunchKernelGGL(wgen_kernel, dim3(3072), dim3(256), 0, stream,
                     tw, wlw, scw, shw, whi, wlo);
  hipLaunchKernelGGL(bgen_kernel, dim3(12), dim3(256), 0, stream,
                     tb, wlb, scb, shb, b_s);
  hipLaunchKernelGGL(ecvt_kernel, dim3(128), dim3(256), 0, stream, emb, embh);
  hipLaunchKernelGGL(proj_mfma_kernel, dim3(768), dim3(256), 0, stream,
                     hs, whi, wlo, b_s, Qhi, Qlo, Khi, Klo, Vthi, Vtlo);
  hipLaunchKernelGGL(attn3_kernel, dim3(512), dim3(512), 0, stream,
                     Qhi, Qlo, Khi, Klo, Vthi, Vtlo, embh, mask, out);
}

// Round 6
// 257.733 us; speedup vs baseline: 1.8234x; 1.4881x over previous
//
#include <hip/hip_runtime.h>
#include <hip/hip_bf16.h>
#include <math.h>

#define D_  1024
#define L_  1024
#define B_  4
#define H_  16
#define HD_ 64

typedef __attribute__((ext_vector_type(4))) short short4_t;
typedef __attribute__((ext_vector_type(8))) short short8_t;
typedef __attribute__((ext_vector_type(4))) float f4;
typedef unsigned short u16;

__device__ __forceinline__ f4 MF(short8_t a, short8_t b, f4 c) {
  return __builtin_amdgcn_mfma_f32_16x16x32_bf16(a, b, c, 0, 0, 0);
}
__device__ __forceinline__ unsigned fbits(float x) { return __builtin_bit_cast(unsigned, x); }
__device__ __forceinline__ float bf2f(unsigned short u) {
  return __builtin_bit_cast(float, (unsigned)u << 16);
}
__device__ __forceinline__ unsigned pack2hi(float x, float y) {
  return (fbits(x) >> 16) | (fbits(y) & 0xFFFF0000u);
}
__device__ __forceinline__ float bfres(float x) {  // x - trunc_bf16(x)
  return x - __builtin_bit_cast(float, fbits(x) & 0xFFFF0000u);
}
__device__ __forceinline__ void gload16(const void* g, void* l) {
  __builtin_amdgcn_global_load_lds(
      (const __attribute__((address_space(1))) unsigned*)g,
      (__attribute__((address_space(3))) unsigned*)l, 16, 0, 0);
}
// two b64 reads forming one MFMA frag; 128B rows, XOR-swizzled (involution,
// matches the gload16 source-side swizzle scol = ((lane&7)^(lane>>3))<<3)
__device__ __forceinline__ short8_t ldsfrag(const char* base, int row, int cb) {
  const char* p = base + row * 128;
  const int sw = (row & 7) << 4;
  union { short4_t q[2]; short8_t v; } u;
  u.q[0] = *(const short4_t*)(p + (cb ^ sw));
  u.q[1] = *(const short4_t*)(p + ((cb + 32) ^ sw));
  return u.v;
}

// ---------------------------------------------------------------------------
// Kernel 1: student weight generation -> bf16 hi/lo planes, K-permuted
// ---------------------------------------------------------------------------
__global__ __launch_bounds__(256) void wgen_kernel(
    const float* __restrict__ tw, const float* __restrict__ wl,
    const float* __restrict__ sc, const float* __restrict__ sh,
    u16* __restrict__ whi, u16* __restrict__ wlo) {
  size_t i4 = (size_t)blockIdx.x * 256 + threadIdx.x;
  size_t e = i4 * 4;
  int p = (int)(e >> 20);
  size_t rem = e & 0xFFFFFu;
  float a0 = wl[p * 2 + 0], a1 = wl[p * 2 + 1];
  float4 t0 = *(const float4*)&tw[((size_t)(p * 2 + 0) << 20) + rem];
  float4 t1 = *(const float4*)&tw[((size_t)(p * 2 + 1) << 20) + rem];
  float4 s4 = *(const float4*)&sc[e];
  float4 h4 = *(const float4*)&sh[e];
  float4 o;
  o.x = tanhf(a0 * t0.x + a1 * t1.x) * s4.x + h4.x;
  o.y = tanhf(a0 * t0.y + a1 * t1.y) * s4.y + h4.y;
  o.z = tanhf(a0 * t0.z + a1 * t1.z) * s4.z + h4.z;
  o.w = tanhf(a0 * t0.w + a1 * t1.w) * s4.w + h4.w;
  const int q = (int)((e & 1023) >> 2);
  const size_t off = (e & ~(size_t)1023) +
                     (q >> 3) * 32 + (q & 3) * 8 + ((q >> 2) & 1) * 4;
  uint2 hi; hi.x = pack2hi(o.x, o.y); hi.y = pack2hi(o.z, o.w);
  *(uint2*)&whi[off] = hi;
  uint2 lo; lo.x = pack2hi(bfres(o.x), bfres(o.y)); lo.y = pack2hi(bfres(o.z), bfres(o.w));
  *(uint2*)&wlo[off] = lo;
}

// ---------------------------------------------------------------------------
// Kernel 2: bias generation (f32)
// ---------------------------------------------------------------------------
__global__ __launch_bounds__(256) void bgen_kernel(
    const float* __restrict__ tb, const float* __restrict__ wl,
    const float* __restrict__ sc, const float* __restrict__ sh,
    float* __restrict__ b_out) {
  int i = blockIdx.x * 256 + threadIdx.x;
  int p = i >> 10;
  int o = i & 1023;
  float v = tanhf(wl[p * 2 + 0] * tb[(p * 2 + 0) * D_ + o] +
                  wl[p * 2 + 1] * tb[(p * 2 + 1) * D_ + o]);
  b_out[i] = v * sc[i] + sh[i];
}

// ---------------------------------------------------------------------------
// Kernel 2b: dist_emb f32 -> bf16 (natural row-major)
// ---------------------------------------------------------------------------
__global__ __launch_bounds__(256) void ecvt_kernel(
    const float* __restrict__ emb, u16* __restrict__ embh) {
  int i4 = blockIdx.x * 256 + threadIdx.x;
  if (i4 >= 32752) return;   // 2047*64/4
  int e = i4 * 4;
  float4 v = *(const float4*)&emb[e];
  uint2 h2; h2.x = pack2hi(v.x, v.y); h2.y = pack2hi(v.z, v.w);
  *(uint2*)&embh[e] = h2;
}

// ---------------------------------------------------------------------------
// Kernel 3: QKV projection, bf16x3 MFMA; writes six bf16 planes:
// Qhi/Qlo, Khi/Klo as [b*16+h][l][hd]; Vthi/Vtlo TRANSPOSED [b*16+h][hd][l].
// ---------------------------------------------------------------------------
__global__ __launch_bounds__(256) void proj_mfma_kernel(
    const float* __restrict__ hs,
    const u16* __restrict__ Bhp, const u16* __restrict__ Blp,
    const float* __restrict__ bias,
    u16* __restrict__ Qhi, u16* __restrict__ Qlo,
    u16* __restrict__ Khi, u16* __restrict__ Klo,
    u16* __restrict__ Vthi, u16* __restrict__ Vtlo) {
  __shared__ u16 Ah[128][32], Al[128][32], Bh[128][32], Bl[128][32];
  const int tid  = threadIdx.x;
  const int lane = tid & 63;
  const int wv   = tid >> 6;
  const int wm   = wv >> 1, wn = wv & 1;
  const int l15  = lane & 15, g = lane >> 4;

  const int bid = (blockIdx.x & 7) * 96 + (blockIdx.x >> 3);  // XCD swizzle
  const int mt = bid & 31, nt = bid >> 5;
  const int m0 = mt * 128, n0 = nt * 128;

  f4 acc[4][4];
#pragma unroll
  for (int i = 0; i < 4; ++i)
#pragma unroll
    for (int j = 0; j < 4; ++j) acc[i][j] = f4{0.f, 0.f, 0.f, 0.f};

#pragma unroll 1
  for (int k0 = 0; k0 < D_; k0 += 32) {
#pragma unroll
    for (int s = 0; s < 4; ++s) {
      int q = wv * 4 + s;
      int plane = q >> 3, rowg = q & 7;
      const u16* src = (plane ? Blp : Bhp) +
                       (size_t)(n0 + rowg * 16 + (lane >> 2)) * 1024 + k0 + (lane & 3) * 8;
      u16* dst = (plane ? &Bl[0][0] : &Bh[0][0]) + rowg * 512;
      gload16(src, dst);
    }
#pragma unroll
    for (int c = 0; c < 4; ++c) {
      int f4id = tid + c * 256;
      int row = f4id >> 3, q4 = f4id & 7;
      float4 v = *(const float4*)&hs[(size_t)(m0 + row) * 1024 + k0 + q4 * 4];
      int col = (q4 & 3) * 8 + ((q4 >> 2) & 1) * 4;
      uint2 hi2; hi2.x = pack2hi(v.x, v.y); hi2.y = pack2hi(v.z, v.w);
      *(uint2*)&Ah[row][col] = hi2;
      uint2 lo2; lo2.x = pack2hi(bfres(v.x), bfres(v.y)); lo2.y = pack2hi(bfres(v.z), bfres(v.w));
      *(uint2*)&Al[row][col] = lo2;
    }
    __syncthreads();

    short8_t ah[4], al[4], bh[4], bl[4];
#pragma unroll
    for (int i = 0; i < 4; ++i) {
      ah[i] = *(const short8_t*)&Ah[wm * 64 + i * 16 + l15][g * 8];
      al[i] = *(const short8_t*)&Al[wm * 64 + i * 16 + l15][g * 8];
      bh[i] = *(const short8_t*)&Bh[wn * 64 + i * 16 + l15][g * 8];
      bl[i] = *(const short8_t*)&Bl[wn * 64 + i * 16 + l15][g * 8];
    }
#pragma unroll
    for (int mi = 0; mi < 4; ++mi)
#pragma unroll
      for (int ni = 0; ni < 4; ++ni) {
        acc[mi][ni] = MF(ah[mi], bh[ni], acc[mi][ni]);
        acc[mi][ni] = MF(ah[mi], bl[ni], acc[mi][ni]);
        acc[mi][ni] = MF(al[mi], bh[ni], acc[mi][ni]);
      }
    __syncthreads();
  }

  // ---- epilogue: per-mi LDS transpose -> coalesced uint2 plane stores ----
  const int p = n0 >> 10;
  const int h0 = (n0 >> 6) & 15;
  const int nbase = n0 + wn * 64;
  float bnv[4];
#pragma unroll
  for (int ni = 0; ni < 4; ++ni) bnv[ni] = bias[nbase + ni * 16 + l15];
  float* T = (float*)&Ah[0][0];   // 32 x 132 f32

#pragma unroll
  for (int mi = 0; mi < 4; ++mi) {
    __syncthreads();
#pragma unroll
    for (int ni = 0; ni < 4; ++ni)
#pragma unroll
      for (int r = 0; r < 4; ++r)
        T[(wm * 16 + 4 * g + r) * 132 + wn * 64 + ni * 16 + l15] =
            acc[mi][ni][r] + bnv[ni];
    __syncthreads();

    if (p < 2) {
      u16* PH = p ? Khi : Qhi;
      u16* PL = p ? Klo : Qlo;
      const int lr = tid >> 3;
      const int m = m0 + (lr >> 4) * 64 + mi * 16 + (lr & 15);
      const int bb = m >> 10, l = m & 1023;
#pragma unroll
      for (int c = 0; c < 4; ++c) {
        const int col = 4 * (tid & 7) + 32 * c;
        const int hd = col & 63, hl = col >> 6;
        float4 v = *(const float4*)&T[lr * 132 + col];
        uint2 hi; hi.x = pack2hi(v.x, v.y); hi.y = pack2hi(v.z, v.w);
        uint2 lo; lo.x = pack2hi(bfres(v.x), bfres(v.y)); lo.y = pack2hi(bfres(v.z), bfres(v.w));
        const size_t ad = ((size_t)(bb * 16 + h0 + hl) << 16) + (size_t)l * 64 + hd;
        *(uint2*)&PH[ad] = hi;
        *(uint2*)&PL[ad] = lo;
      }
    } else {
      const int col = (tid >> 3) & 31;
#pragma unroll
      for (int c = 0; c < 4; ++c) {
        const int cc = col + 32 * c;
        const int hd = cc & 63, hl = cc >> 6;
        const int mq = tid & 7;
        const int lr0 = 4 * mq;
        float vv[4];
#pragma unroll
        for (int k = 0; k < 4; ++k) vv[k] = T[(lr0 + k) * 132 + cc];
        const int m = m0 + (lr0 >> 4) * 64 + mi * 16 + (lr0 & 15);
        const int bb = m >> 10, l = m & 1023;
        uint2 hi; hi.x = pack2hi(vv[0], vv[1]); hi.y = pack2hi(vv[2], vv[3]);
        uint2 lo; lo.x = pack2hi(bfres(vv[0]), bfres(vv[1]));
        lo.y = pack2hi(bfres(vv[2]), bfres(vv[3]));
        const size_t ad = ((size_t)(bb * 16 + h0 + hl) << 16) + (size_t)hd * 1024 + l;
        *(uint2*)&Vthi[ad] = hi;
        *(uint2*)&Vtlo[ad] = lo;
      }
    }
  }
}

// ---------------------------------------------------------------------------
// Kernel 4: fused attention v4 = R3 skeleton (8 waves, banded U/W + gather)
// + gload16 plane staging, K dbuf, V single-buf (staged at iter top),
// E 256-row ring, trimmed 6-d-block band GEMMs. 2 barriers/iter.
// Wave wv = (t, lh, rh). LDS 146 KB.
// ---------------------------------------------------------------------------
#define KD_OFF 0
#define VD_OFF 32768
#define ER_OFF 49152
#define UB_OFF 81920
#define WB_OFF 115712
#define SM4_SIZE 149504

__global__ __launch_bounds__(512, 2) void attn4_kernel(
    const u16* __restrict__ Qhi, const u16* __restrict__ Qlo,
    const u16* __restrict__ Khi, const u16* __restrict__ Klo,
    const u16* __restrict__ Vthi, const u16* __restrict__ Vtlo,
    const u16* __restrict__ embh, const float* __restrict__ mask,
    float* __restrict__ out) {
  __shared__ __align__(16) char sm[SM4_SIZE];
  char* ERb = sm + ER_OFF;

  const int tid  = threadIdx.x;
  const int lane = tid & 63;
  const int wv   = tid >> 6;
  const int t    = wv >> 2;
  const int lh   = (wv >> 1) & 1;
  const int rh   = wv & 1;
  const int l15  = lane & 15;
  const int g    = lane >> 4;
  const int rsub = lane >> 3;
  const int scol = ((lane & 7) ^ (lane >> 3)) << 3;  // u16 units

  const int bid = (blockIdx.x & 7) * 64 + (blockIdx.x >> 3);  // XCD swizzle
  const int lp = bid & 7, h = (bid >> 3) & 15, b = bid >> 7;
  const int l0 = lp * 128;
  const size_t bhoff = (size_t)(b * 16 + h) << 16;
  const float* maskp = mask + b * L_;

  u16* UBt = (u16*)(sm + UB_OFF) + t * 8448;  // [64][132]
  u16* WBt = (u16*)(sm + WB_OFF) + t * 8448;

  // ---- prologue: stage Q (both planes) into ER area, read this wave's frags
#pragma unroll
  for (int s = 0; s < 4; ++s) {
    const int idx = wv * 4 + s;
    const int plane = idx >> 4, rowg = idx & 15;
    const u16* src = (plane ? Qlo : Qhi) + bhoff +
                     (size_t)(l0 + rowg * 8 + rsub) * 64 + scol;
    gload16(src, ERb + (plane * 16 + rowg) * 1024);
  }
  __syncthreads();

  short8_t qfh[2][2], qfl[2][2];   // [nb][kc]
#pragma unroll
  for (int nb = 0; nb < 2; ++nb)
#pragma unroll
    for (int kc = 0; kc < 2; ++kc) {
      const int row = 64 * t + 32 * lh + 16 * nb + l15;
      qfh[nb][kc] = ldsfrag(ERb,         row, 64 * kc + 8 * g);
      qfl[nb][kc] = ldsfrag(ERb + 16384, row, 64 * kc + 8 * g);
    }
  __syncthreads();  // ER area free for the E ring

  // ---- initial staging: K[0] (dbuf slot 0) + E window [dmin0, dmin0+191]
  {
#pragma unroll
    for (int s = 0; s < 2; ++s) {
      const int idx = wv * 2 + s;
      const int plane = idx >> 3, rowg = idx & 7;
      const u16* ks = (plane ? Klo : Khi) + bhoff +
                      (size_t)(rowg * 8 + rsub) * 64 + scol;
      gload16(ks, sm + KD_OFF + plane * 8192 + rowg * 1024);
    }
    const int dmin0 = l0 + 960;
#pragma unroll
    for (int s = 0; s < 3; ++s) {
      const int grp = wv * 3 + s;  // 0..23
      const int slot = (dmin0 + grp * 8) & 255;
      gload16(embh + (size_t)(dmin0 + grp * 8 + rsub) * 64 + scol,
              ERb + slot * 128);
    }
  }

  f4 o_acc[4][2];
#pragma unroll
  for (int i = 0; i < 4; ++i)
#pragma unroll
    for (int j = 0; j < 2; ++j) o_acc[i][j] = f4{0.f, 0.f, 0.f, 0.f};
  float mrun[2] = {-3e38f, -3e38f};
  float lsum[2] = {0.f, 0.f};

#pragma unroll 1
  for (int rt = 0; rt < 16; ++rt) {
    const int r0 = rt * 64;
    const int cur = rt & 1;
    const int dmin = l0 - r0 + 960;

    __syncthreads();  // (bar1) staging for cur drained; prev-iter reads done

    // ---- issue async staging: K[rt+1] + E(rt+1) + V[rt] ----
    if (rt < 15) {
      char* kdn = sm + KD_OFF + (cur ^ 1) * 16384;
#pragma unroll
      for (int s = 0; s < 2; ++s) {
        const int idx = wv * 2 + s;
        const int plane = idx >> 3, rowg = idx & 7;
        const u16* ks = (plane ? Klo : Khi) + bhoff +
                        (size_t)(r0 + 64 + rowg * 8 + rsub) * 64 + scol;
        gload16(ks, kdn + plane * 8192 + rowg * 1024);
      }
      const int rowE = dmin - 64 + wv * 8;
      const int slot = rowE & 255;
      gload16(embh + (size_t)(rowE + rsub) * 64 + scol, ERb + slot * 128);
    }
#pragma unroll
    for (int s = 0; s < 2; ++s) {
      const int idx = wv * 2 + s;
      const int plane = idx >> 3, rowg = idx & 7;
      const u16* vs = (plane ? Vtlo : Vthi) + bhoff +
                      (size_t)(rowg * 8 + rsub) * 1024 + r0 + scol;
      gload16(vs, sm + VD_OFF + plane * 8192 + rowg * 1024);
    }

    // mask prefetch
    float4 mk[2];
#pragma unroll
    for (int mb = 0; mb < 2; ++mb)
      mk[mb] = *(const float4*)&maskp[r0 + 32 * rh + 16 * mb + 4 * g];

    const char* kdc_h = sm + KD_OFF + cur * 16384;
    const char* kdc_l = kdc_h + 8192;

    // ---- QK: S^T = K * Q^T (bf16x3); keep hi K frags for the W GEMM ----
    f4 sacc[2][2];
#pragma unroll
    for (int i = 0; i < 2; ++i)
#pragma unroll
      for (int j = 0; j < 2; ++j) sacc[i][j] = f4{0.f, 0.f, 0.f, 0.f};
    short8_t khf[2][2];
#pragma unroll
    for (int mb = 0; mb < 2; ++mb)
#pragma unroll
      for (int kc = 0; kc < 2; ++kc) {
        const int row = 32 * rh + 16 * mb + l15;
        short8_t ka = ldsfrag(kdc_h, row, 64 * kc + 8 * g);
        short8_t kl = ldsfrag(kdc_l, row, 64 * kc + 8 * g);
        khf[mb][kc] = ka;
#pragma unroll
        for (int nb = 0; nb < 2; ++nb) {
          sacc[mb][nb] = MF(ka, qfh[nb][kc], sacc[mb][nb]);
          sacc[mb][nb] = MF(ka, qfl[nb][kc], sacc[mb][nb]);
          sacc[mb][nb] = MF(kl, qfh[nb][kc], sacc[mb][nb]);
        }
      }

    // ---- U band GEMM: U^T = E * Q^T -> Ub[l][d] (banded, 6 blocks/pair) ----
#pragma unroll
    for (int s = 0; s < 3; ++s) {
      const int dblk = 16 * (2 * lh + 3 * rh + s);
      const int erow = (dmin + 64 * t + dblk + l15) & 255;
      const short8_t eb0 = ldsfrag(ERb, erow, 8 * g);
      const short8_t eb1 = ldsfrag(ERb, erow, 64 + 8 * g);
      f4 au0 = f4{0.f, 0.f, 0.f, 0.f}, au1 = f4{0.f, 0.f, 0.f, 0.f};
      au0 = MF(eb0, qfh[0][0], au0); au0 = MF(eb1, qfh[0][1], au0);
      au1 = MF(eb0, qfh[1][0], au1); au1 = MF(eb1, qfh[1][1], au1);
#pragma unroll
      for (int nb = 0; nb < 2; ++nb) {
        const f4 au = nb ? au1 : au0;
        uint2 w2; w2.x = pack2hi(au[0], au[1]); w2.y = pack2hi(au[2], au[3]);
        *(uint2*)&UBt[(32 * lh + 16 * nb + l15) * 132 + dblk + 4 * g] = w2;
      }
    }

    // ---- W band GEMM: W^T = E * K^T -> Wb[r][d] (banded, 6 blocks/pair) ----
#pragma unroll
    for (int s = 0; s < 3; ++s) {
      const int dblk = 16 * ((2 - 2 * rh) + 3 * lh + s);
      const int erow = (dmin + 64 * t + dblk + l15) & 255;
      const short8_t eb0 = ldsfrag(ERb, erow, 8 * g);
      const short8_t eb1 = ldsfrag(ERb, erow, 64 + 8 * g);
      f4 aw0 = f4{0.f, 0.f, 0.f, 0.f}, aw1 = f4{0.f, 0.f, 0.f, 0.f};
      aw0 = MF(eb0, khf[0][0], aw0); aw0 = MF(eb1, khf[0][1], aw0);
      aw1 = MF(eb0, khf[1][0], aw1); aw1 = MF(eb1, khf[1][1], aw1);
#pragma unroll
      for (int mb = 0; mb < 2; ++mb) {
        const f4 aw = mb ? aw1 : aw0;
        uint2 w2; w2.x = pack2hi(aw[0], aw[1]); w2.y = pack2hi(aw[2], aw[3]);
        *(uint2*)&WBt[(32 * rh + 16 * mb + l15) * 132 + dblk + 4 * g] = w2;
      }
    }
    __syncthreads();  // (bar2) U/W visible; staging for this iter drained

    // ---- assembly + online softmax (per-wave rh chain) ----
    float pbuf[2][2][4];
#pragma unroll
    for (int nb = 0; nb < 2; ++nb) {
      const int lA = 32 * lh + 16 * nb + l15;
      float sv[2][4];
      float ml = -3e38f;
#pragma unroll
      for (int mb = 0; mb < 2; ++mb) {
        const int rr = 32 * rh + 16 * mb + 4 * g;
        const int dbase = lA + 63 - rr;
        const float mka[4] = {mk[mb].x, mk[mb].y, mk[mb].z, mk[mb].w};
#pragma unroll
        for (int j = 0; j < 4; ++j) {
          const float uu = bf2f(UBt[lA * 132 + dbase - j]);
          const float ww = bf2f(WBt[(rr + j) * 132 + dbase - j]);
          float s = (sacc[mb][nb][j] + uu + ww) * 0.125f + mka[j];
          sv[mb][j] = s;
          ml = fmaxf(ml, s);
        }
      }
      ml = fmaxf(ml, __shfl_xor(ml, 16));
      ml = fmaxf(ml, __shfl_xor(ml, 32));
      const float mn = fmaxf(mrun[nb], ml);
      const float rs = __expf(mrun[nb] - mn);
      float ps = 0.f;
#pragma unroll
      for (int mb = 0; mb < 2; ++mb)
#pragma unroll
        for (int j = 0; j < 4; ++j) {
          const float pv = __expf(sv[mb][j] - mn);
          pbuf[nb][mb][j] = pv;
          ps += pv;
        }
      ps += __shfl_xor(ps, 16);
      ps += __shfl_xor(ps, 32);
      lsum[nb] = lsum[nb] * rs + ps;
      mrun[nb] = mn;
#pragma unroll
      for (int mbd = 0; mbd < 4; ++mbd) {
        o_acc[mbd][nb][0] *= rs; o_acc[mbd][nb][1] *= rs;
        o_acc[mbd][nb][2] *= rs; o_acc[mbd][nb][3] *= rs;
      }
    }

    // ---- P fragments (hi/lo) from registers; PV ----
    short8_t pf[2], pl_[2];
#pragma unroll
    for (int nb = 0; nb < 2; ++nb) {
      union { unsigned u[4]; short8_t v; } uh, ul;
      uh.u[0] = pack2hi(pbuf[nb][0][0], pbuf[nb][0][1]);
      uh.u[1] = pack2hi(pbuf[nb][0][2], pbuf[nb][0][3]);
      uh.u[2] = pack2hi(pbuf[nb][1][0], pbuf[nb][1][1]);
      uh.u[3] = pack2hi(pbuf[nb][1][2], pbuf[nb][1][3]);
      pf[nb] = uh.v;
      ul.u[0] = pack2hi(bfres(pbuf[nb][0][0]), bfres(pbuf[nb][0][1]));
      ul.u[1] = pack2hi(bfres(pbuf[nb][0][2]), bfres(pbuf[nb][0][3]));
      ul.u[2] = pack2hi(bfres(pbuf[nb][1][0]), bfres(pbuf[nb][1][1]));
      ul.u[3] = pack2hi(bfres(pbuf[nb][1][2]), bfres(pbuf[nb][1][3]));
      pl_[nb] = ul.v;
    }
    const char* vdc_h = sm + VD_OFF;
    const char* vdc_l = vdc_h + 8192;
#pragma unroll
    for (int mbd = 0; mbd < 4; ++mbd) {
      short8_t vh = ldsfrag(vdc_h, 16 * mbd + l15, 64 * rh + 8 * g);
      short8_t vl = ldsfrag(vdc_l, 16 * mbd + l15, 64 * rh + 8 * g);
#pragma unroll
      for (int nb = 0; nb < 2; ++nb) {
        o_acc[mbd][nb] = MF(vh, pf[nb], o_acc[mbd][nb]);
        o_acc[mbd][nb] = MF(vh, pl_[nb], o_acc[mbd][nb]);
        o_acc[mbd][nb] = MF(vl, pf[nb], o_acc[mbd][nb]);
      }
    }
  }

  // ---- epilogue: merge the two rh chains (partner wave wv^1), store ----
  __syncthreads();
  float* mbuf = (float*)ERb;
  float* obuf = (float*)(sm + UB_OFF);   // [256][32] f32 = 32 KB
  if (g == 0) {
#pragma unroll
    for (int nb = 0; nb < 2; ++nb) {
      mbuf[((wv * 2 + nb) * 16 + l15) * 2 + 0] = mrun[nb];
      mbuf[((wv * 2 + nb) * 16 + l15) * 2 + 1] = lsum[nb];
    }
  }
  __syncthreads();
  const int pw = wv ^ 1;
  float alpha[2], ltot[2];
#pragma unroll
  for (int nb = 0; nb < 2; ++nb) {
    float m2 = mbuf[((pw * 2 + nb) * 16 + l15) * 2 + 0];
    float s2 = mbuf[((pw * 2 + nb) * 16 + l15) * 2 + 1];
    float M = fmaxf(mrun[nb], m2);
    alpha[nb] = __expf(mrun[nb] - M);
    ltot[nb] = lsum[nb] * alpha[nb] + s2 * __expf(m2 - M);
  }
  const int pair = wv >> 1;   // (t, lh)
  if (rh == 1) {
#pragma unroll
    for (int mbd = 0; mbd < 4; ++mbd)
#pragma unroll
      for (int nb = 0; nb < 2; ++nb)
#pragma unroll
        for (int j = 0; j < 4; ++j)
          obuf[(pair * 64 + 16 * mbd + 4 * g + j) * 32 + 16 * nb + l15] =
              o_acc[mbd][nb][j] * alpha[nb];
  }
  __syncthreads();
  if (rh == 0) {
#pragma unroll
    for (int mbd = 0; mbd < 4; ++mbd)
#pragma unroll
      for (int nb = 0; nb < 2; ++nb) {
        const int lgl = l0 + 64 * t + 32 * lh + 16 * nb + l15;
        const float inv = 1.f / ltot[nb];
        float tmp[4];
#pragma unroll
        for (int j = 0; j < 4; ++j)
          tmp[j] = (o_acc[mbd][nb][j] * alpha[nb] +
                    obuf[(pair * 64 + 16 * mbd + 4 * g + j) * 32 + 16 * nb + l15]) * inv;
        float4 ov; ov.x = tmp[0]; ov.y = tmp[1]; ov.z = tmp[2]; ov.w = tmp[3];
        *(float4*)&out[(size_t)(b * L_ + lgl) * D_ + h * HD_ + 16 * mbd + 4 * g] = ov;
      }
  }
}

// ---------------------------------------------------------------------------
extern "C" void kernel_launch(void* const* d_in, const int* in_sizes, int n_in,
                              void* d_out, int out_size, void* d_ws, size_t ws_size,
                              hipStream_t stream) {
  const float* hs   = (const float*)d_in[0];
  const float* mask = (const float*)d_in[1];
  const float* tw   = (const float*)d_in[2];
  const float* wlw  = (const float*)d_in[3];
  const float* scw  = (const float*)d_in[4];
  const float* shw  = (const float*)d_in[5];
  const float* tb   = (const float*)d_in[6];
  const float* wlb  = (const float*)d_in[7];
  const float* scb  = (const float*)d_in[8];
  const float* shb  = (const float*)d_in[9];
  const float* emb  = (const float*)d_in[10];
  float* out = (float*)d_out;

  char* W = (char*)d_ws;
  float* b_s = (float*)W;                         // 3072 f32
  u16* whi  = (u16*)(W + 12288);
  u16* wlo  = whi + 3145728;
  u16* embh = wlo + 3145728;                      // 2048 rows x 64 (row 2047 pad)
  u16* Qhi  = embh + 131072;
  u16* Qlo  = Qhi + 4194304;
  u16* Khi  = Qlo + 4194304;
  u16* Klo  = Khi + 4194304;
  u16* Vthi = Klo + 4194304;
  u16* Vtlo = Vthi + 4194304;                     // total ~63 MB

  hipLaunchKernelGGL(wgen_kernel, dim3(3072), dim3(256), 0, stream,
                     tw, wlw, scw, shw, whi, wlo);
  hipLaunchKernelGGL(bgen_kernel, dim3(12), dim3(256), 0, stream,
                     tb, wlb, scb, shb, b_s);
  hipLaunchKernelGGL(ecvt_kernel, dim3(128), dim3(256), 0, stream, emb, embh);
  hipLaunchKernelGGL(proj_mfma_kernel, dim3(768), dim3(256), 0, stream,
                     hs, whi, wlo, b_s, Qhi, Qlo, Khi, Klo, Vthi, Vtlo);
  hipLaunchKernelGGL(attn4_kernel, dim3(512), dim3(512), 0, stream,
                     Qhi, Qlo, Khi, Klo, Vthi, Vtlo, embh, mask, out);
}